// Round 1
// baseline (607.591 us; speedup 1.0000x reference)
//
#include <hip/hip_runtime.h>
#include <stdint.h>

#define BSZ 2
#define LSEQ 2048
#define DMOD 1024
#define NH 16
#define HDSZ 64

typedef __attribute__((ext_vector_type(8))) short short8;
typedef __attribute__((ext_vector_type(4))) float f32x4;
typedef __attribute__((ext_vector_type(4))) unsigned short u16x4;

#define MFMA16(a, b, c) __builtin_amdgcn_mfma_f32_16x16x32_bf16((a), (b), (c), 0, 0, 0)

__device__ __forceinline__ unsigned short f2bf(float f) {
  union { float f; unsigned u; } x; x.f = f;
  unsigned u = x.u + 0x7fffu + ((x.u >> 16) & 1u);
  return (unsigned short)(u >> 16);
}

// ---------------- fp32 -> bf16 conversion ----------------
__global__ __launch_bounds__(256) void cvt_bf16(const float* __restrict__ in,
                                                unsigned short* __restrict__ out, int n) {
  int i = (blockIdx.x * 256 + threadIdx.x) * 4;
  if (i >= n) return;
  f32x4 v = *(const f32x4*)(in + i);
  u16x4 o;
  o[0] = f2bf(v[0]); o[1] = f2bf(v[1]); o[2] = f2bf(v[2]); o[3] = f2bf(v[3]);
  *(u16x4*)(out + i) = o;
}

// ---------------- GEMM: C = A * W^T + bias (A: MxK, W: NxK, bf16, fp32 acc) --------
// 128x128 tile, BK=32, 4 waves (2x2 of 64x64), mfma 16x16x32 bf16.
// z-fused: blockIdx.z selects one of three (A,W,bias,C,scale) sets.
template <int OUTF32>
__global__ __launch_bounds__(256) void gemm_bt(
    const unsigned short* __restrict__ A0, const unsigned short* __restrict__ A1,
    const unsigned short* __restrict__ A2,
    const unsigned short* __restrict__ W0, const unsigned short* __restrict__ W1,
    const unsigned short* __restrict__ W2,
    const float* __restrict__ b0, const float* __restrict__ b1, const float* __restrict__ b2,
    void* __restrict__ C0, void* __restrict__ C1, void* __restrict__ C2,
    float s0, float s1, float s2, int M, int N, int K) {
  const int z = blockIdx.z;
  const unsigned short* A = (z == 0) ? A0 : ((z == 1) ? A1 : A2);
  const unsigned short* W = (z == 0) ? W0 : ((z == 1) ? W1 : W2);
  const float* bias = (z == 0) ? b0 : ((z == 1) ? b1 : b2);
  void* Cout = (z == 0) ? C0 : ((z == 1) ? C1 : C2);
  const float scale = (z == 0) ? s0 : ((z == 1) ? s1 : s2);

  // pad rows to 40 elems (80B): quarter-wave conflict-free ds_read_b128, 16B aligned
  __shared__ unsigned short As[128 * 40];
  __shared__ unsigned short Bs[128 * 40];

  const int tid = threadIdx.x;
  const int lane = tid & 63;
  const int wid = tid >> 6;
  const int bm = blockIdx.x, bn = blockIdx.y;
  const int wm = (wid >> 1) * 64, wn = (wid & 1) * 64;

  f32x4 acc[4][4];
#pragma unroll
  for (int i = 0; i < 4; i++)
#pragma unroll
    for (int j = 0; j < 4; j++) acc[i][j] = (f32x4){0.f, 0.f, 0.f, 0.f};

  const int r0 = tid >> 2;        // 0..63
  const int c0 = (tid & 3) * 8;   // 0,8,16,24
  const unsigned short* Ag = A + (size_t)(bm * 128 + r0) * K + c0;
  const unsigned short* Bg = W + (size_t)(bn * 128 + r0) * K + c0;

  // prefetch tile 0 into regs
  short8 va[2], vb[2];
#pragma unroll
  for (int j = 0; j < 2; j++) {
    va[j] = *(const short8*)(Ag + (size_t)(j * 64) * K);
    vb[j] = *(const short8*)(Bg + (size_t)(j * 64) * K);
  }

  for (int k0 = 0; k0 < K; k0 += 32) {
#pragma unroll
    for (int j = 0; j < 2; j++) {
      *(short8*)&As[(j * 64 + r0) * 40 + c0] = va[j];
      *(short8*)&Bs[(j * 64 + r0) * 40 + c0] = vb[j];
    }
    __syncthreads();
    if (k0 + 32 < K) {  // prefetch next tile (overlaps with MFMA below)
#pragma unroll
      for (int j = 0; j < 2; j++) {
        va[j] = *(const short8*)(Ag + (size_t)(j * 64) * K + k0 + 32);
        vb[j] = *(const short8*)(Bg + (size_t)(j * 64) * K + k0 + 32);
      }
    }
    short8 af[4], bf[4];
#pragma unroll
    for (int i = 0; i < 4; i++)
      af[i] = *(const short8*)&As[(wm + i * 16 + (lane & 15)) * 40 + (lane >> 4) * 8];
#pragma unroll
    for (int i = 0; i < 4; i++)
      bf[i] = *(const short8*)&Bs[(wn + i * 16 + (lane & 15)) * 40 + (lane >> 4) * 8];
#pragma unroll
    for (int i = 0; i < 4; i++)
#pragma unroll
      for (int j = 0; j < 4; j++) acc[i][j] = MFMA16(af[i], bf[j], acc[i][j]);
    __syncthreads();
  }

  // epilogue: C row = (lane>>4)*4+r, col = lane&15 within each 16x16 fragment
  const int crow = bm * 128 + wm + (lane >> 4) * 4;
#pragma unroll
  for (int j = 0; j < 4; j++) {
    const int col = bn * 128 + wn + j * 16 + (lane & 15);
    const float bv = bias[col];
#pragma unroll
    for (int i = 0; i < 4; i++) {
#pragma unroll
      for (int r = 0; r < 4; r++) {
        float vvv = (acc[i][j][r] + bv) * scale;
        const size_t off = (size_t)(crow + i * 16 + r) * N + col;
        if (OUTF32)
          ((float*)Cout)[off] = vvv;
        else
          ((unsigned short*)Cout)[off] = f2bf(vvv);
      }
    }
  }
}

// ---------------- V transpose: (B,L,D) bf16 -> (B,D,L) bf16 ----------------
__global__ __launch_bounds__(256) void transpose_v(const unsigned short* __restrict__ Vp,
                                                   unsigned short* __restrict__ Vt) {
  __shared__ unsigned short T[64][72];
  const int tid = threadIdx.x;
  const int l0 = blockIdx.x * 64;
  const int d0 = blockIdx.y * 64;
  const int b = blockIdx.z;
  const int r = tid >> 2, c = (tid & 3) * 16;
  const unsigned short* src =
      Vp + (size_t)b * LSEQ * DMOD + (size_t)(l0 + r) * DMOD + d0 + c;
  *(short8*)&T[r][c] = *(const short8*)(src);
  *(short8*)&T[r][c + 8] = *(const short8*)(src + 8);
  __syncthreads();
  unsigned short tmp[16];
#pragma unroll
  for (int x = 0; x < 16; x++) tmp[x] = T[c + x][r];
  unsigned short* dst = Vt + (size_t)b * DMOD * LSEQ + (size_t)(d0 + r) * LSEQ + l0 + c;
  *(short8*)(dst) = *(short8*)&tmp[0];
  *(short8*)(dst + 8) = *(short8*)&tmp[8];
}

// ---------------- fused attention ----------------
// grid: (L/128, B*H). 4 waves, each owns 32 q-rows.
// Sweep 1: S = Q*K^T (scale pre-folded into Q), per-row sum of masked exp(S).
// Sweep 2: recompute S, attn = exp(S)*inv -> global fp32 + bf16 in LDS, PV MFMA.
// No max subtraction: scores here are O(+-12), exp() is safe in fp32 and
// mathematically identical to softmax-with-max.
__global__ __launch_bounds__(256) void attn_kernel(
    const unsigned short* __restrict__ Qp, const unsigned short* __restrict__ Kp,
    const unsigned short* __restrict__ Vt, const int* __restrict__ mask,
    float* __restrict__ attn_out, unsigned short* __restrict__ ctx) {
  __shared__ unsigned short Ks[64][72];
  __shared__ unsigned short Vs[64][72];
  __shared__ unsigned short Ps[4][32][72];

  const int tid = threadIdx.x, lane = tid & 63, wid = tid >> 6;
  const int q0 = blockIdx.x * 128;
  const int bh = blockIdx.y;
  const int b = bh >> 4, h = bh & 15;

  const unsigned short* Qh = Qp + (size_t)b * LSEQ * DMOD + h * HDSZ;
  const unsigned short* Kh = Kp + (size_t)b * LSEQ * DMOD + h * HDSZ;
  const unsigned short* Vh = Vt + (size_t)b * DMOD * LSEQ + (size_t)h * HDSZ * LSEQ;
  const int* mb = mask + (size_t)b * LSEQ * LSEQ;
  float* ah = attn_out + (size_t)bh * LSEQ * LSEQ;

  const int wq0 = q0 + wid * 32;

  // Q fragments live in registers for the whole kernel
  short8 qf[2][2];
#pragma unroll
  for (int fm = 0; fm < 2; fm++)
#pragma unroll
    for (int ks = 0; ks < 2; ks++)
      qf[fm][ks] = *(const short8*)(Qh + (size_t)(wq0 + fm * 16 + (lane & 15)) * DMOD +
                                    ks * 32 + (lane >> 4) * 8);

  const int sr = tid >> 2, sc = (tid & 3) * 16;

  // ---------- sweep 1: denominators ----------
  float den[2][4] = {{0.f, 0.f, 0.f, 0.f}, {0.f, 0.f, 0.f, 0.f}};
  for (int kt = 0; kt < LSEQ / 64; ++kt) {
    const int k0 = kt * 64;
    __syncthreads();
    {
      const unsigned short* s = Kh + (size_t)(k0 + sr) * DMOD + sc;
      *(short8*)&Ks[sr][sc] = *(const short8*)(s);
      *(short8*)&Ks[sr][sc + 8] = *(const short8*)(s + 8);
    }
    __syncthreads();
    short8 kf[4][2];
#pragma unroll
    for (int fn = 0; fn < 4; fn++)
#pragma unroll
      for (int ks = 0; ks < 2; ks++)
        kf[fn][ks] = *(const short8*)&Ks[fn * 16 + (lane & 15)][ks * 32 + (lane >> 4) * 8];
#pragma unroll
    for (int fm = 0; fm < 2; fm++) {
#pragma unroll
      for (int fn = 0; fn < 4; fn++) {
        f32x4 s = (f32x4){0.f, 0.f, 0.f, 0.f};
        s = MFMA16(qf[fm][0], kf[fn][0], s);
        s = MFMA16(qf[fm][1], kf[fn][1], s);
        const int kcol = k0 + fn * 16 + (lane & 15);
#pragma unroll
        for (int r = 0; r < 4; r++) {
          const int qrow = wq0 + fm * 16 + (lane >> 4) * 4 + r;
          const int m = mb[(size_t)qrow * LSEQ + kcol];
          den[fm][r] += (m != 0) ? __expf(s[r]) : 0.f;
        }
      }
    }
  }
  float inv[2][4];
#pragma unroll
  for (int fm = 0; fm < 2; fm++)
#pragma unroll
    for (int r = 0; r < 4; r++) {
      float v = den[fm][r];
      v += __shfl_xor(v, 1);
      v += __shfl_xor(v, 2);
      v += __shfl_xor(v, 4);
      v += __shfl_xor(v, 8);
      inv[fm][r] = 1.0f / v;
    }

  // ---------- sweep 2: attn write + PV ----------
  f32x4 oacc[2][4];
#pragma unroll
  for (int fm = 0; fm < 2; fm++)
#pragma unroll
    for (int fd = 0; fd < 4; fd++) oacc[fm][fd] = (f32x4){0.f, 0.f, 0.f, 0.f};

  for (int kt = 0; kt < LSEQ / 64; ++kt) {
    const int k0 = kt * 64;
    __syncthreads();
    {
      const unsigned short* s = Kh + (size_t)(k0 + sr) * DMOD + sc;
      *(short8*)&Ks[sr][sc] = *(const short8*)(s);
      *(short8*)&Ks[sr][sc + 8] = *(const short8*)(s + 8);
      const unsigned short* sv = Vh + (size_t)sr * LSEQ + k0 + sc;
      *(short8*)&Vs[sr][sc] = *(const short8*)(sv);
      *(short8*)&Vs[sr][sc + 8] = *(const short8*)(sv + 8);
    }
    __syncthreads();
    short8 kf[4][2];
#pragma unroll
    for (int fn = 0; fn < 4; fn++)
#pragma unroll
      for (int ks = 0; ks < 2; ks++)
        kf[fn][ks] = *(const short8*)&Ks[fn * 16 + (lane & 15)][ks * 32 + (lane >> 4) * 8];
#pragma unroll
    for (int fm = 0; fm < 2; fm++) {
#pragma unroll
      for (int fn = 0; fn < 4; fn++) {
        f32x4 s = (f32x4){0.f, 0.f, 0.f, 0.f};
        s = MFMA16(qf[fm][0], kf[fn][0], s);
        s = MFMA16(qf[fm][1], kf[fn][1], s);
        const int kcol = k0 + fn * 16 + (lane & 15);
#pragma unroll
        for (int r = 0; r < 4; r++) {
          const int qrow = wq0 + fm * 16 + (lane >> 4) * 4 + r;
          const int m = mb[(size_t)qrow * LSEQ + kcol];
          const float a = (m != 0) ? __expf(s[r]) * inv[fm][r] : 0.f;
          ah[(size_t)qrow * LSEQ + kcol] = a;
          Ps[wid][fm * 16 + (lane >> 4) * 4 + r][fn * 16 + (lane & 15)] = f2bf(a);
        }
      }
    }
    // PV: A = Ps (wave-private, lgkmcnt ordering handled by compiler), B = Vs
#pragma unroll
    for (int fm = 0; fm < 2; fm++) {
      short8 pa[2];
#pragma unroll
      for (int ks = 0; ks < 2; ks++)
        pa[ks] = *(const short8*)&Ps[wid][fm * 16 + (lane & 15)][ks * 32 + (lane >> 4) * 8];
#pragma unroll
      for (int fd = 0; fd < 4; fd++) {
#pragma unroll
        for (int ks = 0; ks < 2; ks++) {
          short8 vf = *(const short8*)&Vs[fd * 16 + (lane & 15)][ks * 32 + (lane >> 4) * 8];
          oacc[fm][fd] = MFMA16(pa[ks], vf, oacc[fm][fd]);
        }
      }
    }
  }

  unsigned short* ch = ctx + (size_t)b * LSEQ * DMOD + h * HDSZ;
#pragma unroll
  for (int fm = 0; fm < 2; fm++)
#pragma unroll
    for (int fd = 0; fd < 4; fd++)
#pragma unroll
      for (int r = 0; r < 4; r++) {
        const int qrow = wq0 + fm * 16 + (lane >> 4) * 4 + r;
        ch[(size_t)qrow * DMOD + fd * 16 + (lane & 15)] = f2bf(oacc[fm][fd][r]);
      }
}

// ---------------- launcher ----------------
extern "C" void kernel_launch(void* const* d_in, const int* in_sizes, int n_in,
                              void* d_out, int out_size, void* d_ws, size_t ws_size,
                              hipStream_t stream) {
  const float* q = (const float*)d_in[0];
  const float* k = (const float*)d_in[1];
  const float* v = (const float*)d_in[2];
  const int* mask = (const int*)d_in[3];
  const float* Wq = (const float*)d_in[4];
  const float* bq = (const float*)d_in[5];
  const float* Wk = (const float*)d_in[6];
  const float* bk = (const float*)d_in[7];
  const float* Wv = (const float*)d_in[8];
  const float* bv = (const float*)d_in[9];
  const float* Wo = (const float*)d_in[10];
  const float* bo = (const float*)d_in[11];

  float* out = (float*)d_out;
  float* attn = out + (size_t)BSZ * LSEQ * DMOD;  // 537 MB attn region

  const size_t NQKV = (size_t)BSZ * LSEQ * DMOD;  // 4,194,304
  const size_t NW = (size_t)DMOD * DMOD;          // 1,048,576

  // Scratch that is dead before the attention kernel runs lives INSIDE the
  // attn output region (attention overwrites all of it with final values).
  unsigned short* qb = (unsigned short*)attn;
  unsigned short* kb = qb + NQKV;
  unsigned short* vb = kb + NQKV;
  unsigned short* Wqb = vb + NQKV;
  unsigned short* Wkb = Wqb + NW;
  unsigned short* Wvb = Wkb + NW;
  unsigned short* Vp = Wvb + NW;  // bf16 projected V (pre-transpose)

  // Scratch that must survive the attention kernel lives in d_ws (~35.7 MB).
  unsigned short* Qp = (unsigned short*)d_ws;
  unsigned short* Kp = Qp + NQKV;
  unsigned short* Vt = Kp + NQKV;
  unsigned short* ctx = Vt + NQKV;
  unsigned short* Wob = ctx + NQKV;

  // 1) convert to bf16
  cvt_bf16<<<dim3(NQKV / 4 / 256), 256, 0, stream>>>(q, qb, (int)NQKV);
  cvt_bf16<<<dim3(NQKV / 4 / 256), 256, 0, stream>>>(k, kb, (int)NQKV);
  cvt_bf16<<<dim3(NQKV / 4 / 256), 256, 0, stream>>>(v, vb, (int)NQKV);
  cvt_bf16<<<dim3(NW / 4 / 256), 256, 0, stream>>>(Wq, Wqb, (int)NW);
  cvt_bf16<<<dim3(NW / 4 / 256), 256, 0, stream>>>(Wk, Wkb, (int)NW);
  cvt_bf16<<<dim3(NW / 4 / 256), 256, 0, stream>>>(Wv, Wvb, (int)NW);
  cvt_bf16<<<dim3(NW / 4 / 256), 256, 0, stream>>>(Wo, Wob, (int)NW);

  // 2) QKV projections (z-fused). 1/sqrt(HD)=0.125 folded into Q (exact pow2).
  gemm_bt<0><<<dim3(32, 8, 3), 256, 0, stream>>>(
      qb, kb, vb, Wqb, Wkb, Wvb, bq, bk, bv, (void*)Qp, (void*)Kp, (void*)Vp,
      0.125f, 1.0f, 1.0f, BSZ * LSEQ, DMOD, DMOD);

  // 3) V transpose -> (B, D, L)
  transpose_v<<<dim3(LSEQ / 64, DMOD / 64, BSZ), 256, 0, stream>>>(Vp, Vt);

  // 4) fused attention: writes full attn (fp32) + ctx (bf16)
  attn_kernel<<<dim3(LSEQ / 128, BSZ * NH), 256, 0, stream>>>(Qp, Kp, Vt, mask, attn, ctx);

  // 5) output projection -> d_out[0 : B*L*D]
  gemm_bt<1><<<dim3(32, 8, 1), 256, 0, stream>>>(
      ctx, ctx, ctx, Wob, Wob, Wob, bo, bo, bo, (void*)out, (void*)out, (void*)out,
      1.0f, 1.0f, 1.0f, BSZ * LSEQ, DMOD, DMOD);
}

// Round 2
// 409.824 us; speedup vs baseline: 1.4826x; 1.4826x over previous
//
#include <hip/hip_runtime.h>
#include <stdint.h>

#define BSZ 2
#define LSEQ 2048
#define DMOD 1024
#define NH 16
#define HDSZ 64

typedef __attribute__((ext_vector_type(8))) short short8;
typedef __attribute__((ext_vector_type(4))) float f32x4;
typedef __attribute__((ext_vector_type(4))) unsigned short u16x4;
typedef __attribute__((ext_vector_type(4))) int i32x4;

#define MFMA16(a, b, c) __builtin_amdgcn_mfma_f32_16x16x32_bf16((a), (b), (c), 0, 0, 0)

__device__ __forceinline__ unsigned short f2bf(float f) {
  union { float f; unsigned u; } x; x.f = f;
  unsigned u = x.u + 0x7fffu + ((x.u >> 16) & 1u);
  return (unsigned short)(u >> 16);
}

// ---------------- fp32 -> bf16 conversion ----------------
__global__ __launch_bounds__(256) void cvt_bf16(const float* __restrict__ in,
                                                unsigned short* __restrict__ out, int n) {
  int i = (blockIdx.x * 256 + threadIdx.x) * 4;
  if (i >= n) return;
  f32x4 v = *(const f32x4*)(in + i);
  u16x4 o;
  o[0] = f2bf(v[0]); o[1] = f2bf(v[1]); o[2] = f2bf(v[2]); o[3] = f2bf(v[3]);
  *(u16x4*)(out + i) = o;
}

// ---------------- GEMM: C = A * W^T + bias (A: MxK, W: NxK, bf16, fp32 acc) --------
template <int OUTF32>
__global__ __launch_bounds__(256) void gemm_bt(
    const unsigned short* __restrict__ A0, const unsigned short* __restrict__ A1,
    const unsigned short* __restrict__ A2,
    const unsigned short* __restrict__ W0, const unsigned short* __restrict__ W1,
    const unsigned short* __restrict__ W2,
    const float* __restrict__ b0, const float* __restrict__ b1, const float* __restrict__ b2,
    void* __restrict__ C0, void* __restrict__ C1, void* __restrict__ C2,
    float s0, float s1, float s2, int M, int N, int K) {
  const int z = blockIdx.z;
  const unsigned short* A = (z == 0) ? A0 : ((z == 1) ? A1 : A2);
  const unsigned short* W = (z == 0) ? W0 : ((z == 1) ? W1 : W2);
  const float* bias = (z == 0) ? b0 : ((z == 1) ? b1 : b2);
  void* Cout = (z == 0) ? C0 : ((z == 1) ? C1 : C2);
  const float scale = (z == 0) ? s0 : ((z == 1) ? s1 : s2);

  __shared__ unsigned short As[128 * 40];
  __shared__ unsigned short Bs[128 * 40];

  const int tid = threadIdx.x;
  const int lane = tid & 63;
  const int wid = tid >> 6;
  const int bm = blockIdx.x, bn = blockIdx.y;
  const int wm = (wid >> 1) * 64, wn = (wid & 1) * 64;

  f32x4 acc[4][4];
#pragma unroll
  for (int i = 0; i < 4; i++)
#pragma unroll
    for (int j = 0; j < 4; j++) acc[i][j] = (f32x4){0.f, 0.f, 0.f, 0.f};

  const int r0 = tid >> 2;
  const int c0 = (tid & 3) * 8;
  const unsigned short* Ag = A + (size_t)(bm * 128 + r0) * K + c0;
  const unsigned short* Bg = W + (size_t)(bn * 128 + r0) * K + c0;

  short8 va[2], vb[2];
#pragma unroll
  for (int j = 0; j < 2; j++) {
    va[j] = *(const short8*)(Ag + (size_t)(j * 64) * K);
    vb[j] = *(const short8*)(Bg + (size_t)(j * 64) * K);
  }

  for (int k0 = 0; k0 < K; k0 += 32) {
#pragma unroll
    for (int j = 0; j < 2; j++) {
      *(short8*)&As[(j * 64 + r0) * 40 + c0] = va[j];
      *(short8*)&Bs[(j * 64 + r0) * 40 + c0] = vb[j];
    }
    __syncthreads();
    if (k0 + 32 < K) {
#pragma unroll
      for (int j = 0; j < 2; j++) {
        va[j] = *(const short8*)(Ag + (size_t)(j * 64) * K + k0 + 32);
        vb[j] = *(const short8*)(Bg + (size_t)(j * 64) * K + k0 + 32);
      }
    }
    short8 af[4], bf[4];
#pragma unroll
    for (int i = 0; i < 4; i++)
      af[i] = *(const short8*)&As[(wm + i * 16 + (lane & 15)) * 40 + (lane >> 4) * 8];
#pragma unroll
    for (int i = 0; i < 4; i++)
      bf[i] = *(const short8*)&Bs[(wn + i * 16 + (lane & 15)) * 40 + (lane >> 4) * 8];
#pragma unroll
    for (int i = 0; i < 4; i++)
#pragma unroll
      for (int j = 0; j < 4; j++) acc[i][j] = MFMA16(af[i], bf[j], acc[i][j]);
    __syncthreads();
  }

  const int crow = bm * 128 + wm + (lane >> 4) * 4;
#pragma unroll
  for (int j = 0; j < 4; j++) {
    const int col = bn * 128 + wn + j * 16 + (lane & 15);
    const float bv = bias[col];
#pragma unroll
    for (int i = 0; i < 4; i++) {
#pragma unroll
      for (int r = 0; r < 4; r++) {
        float vvv = (acc[i][j][r] + bv) * scale;
        const size_t off = (size_t)(crow + i * 16 + r) * N + col;
        if (OUTF32)
          ((float*)Cout)[off] = vvv;
        else
          ((unsigned short*)Cout)[off] = f2bf(vvv);
      }
    }
  }
}

// ---------------- V transpose: (B,L,D) bf16 -> (B,D,L) bf16 ----------------
__global__ __launch_bounds__(256) void transpose_v(const unsigned short* __restrict__ Vp,
                                                   unsigned short* __restrict__ Vt) {
  __shared__ unsigned short T[64][72];
  const int tid = threadIdx.x;
  const int l0 = blockIdx.x * 64;
  const int d0 = blockIdx.y * 64;
  const int b = blockIdx.z;
  const int r = tid >> 2, c = (tid & 3) * 16;
  const unsigned short* src =
      Vp + (size_t)b * LSEQ * DMOD + (size_t)(l0 + r) * DMOD + d0 + c;
  *(short8*)&T[r][c] = *(const short8*)(src);
  *(short8*)&T[r][c + 8] = *(const short8*)(src + 8);
  __syncthreads();
  unsigned short tmp[16];
#pragma unroll
  for (int x = 0; x < 16; x++) tmp[x] = T[c + x][r];
  unsigned short* dst = Vt + (size_t)b * DMOD * LSEQ + (size_t)(d0 + r) * LSEQ + l0 + c;
  *(short8*)(dst) = *(short8*)&tmp[0];
  *(short8*)(dst + 8) = *(short8*)&tmp[8];
}

// ---------------- fused attention (v2: S^T layout, 64 q-rows/block) ----------------
// grid: (L/64, B*H). 4 waves, each owns 16 q-rows.
// S^T = mfma(K_rows, Q_rows): lane holds 4 CONSECUTIVE k for a fixed q-row
// -> int4 mask load, f32x4 attn store, packed b64 Ps write, 2-shuffle denom.
// No max subtraction needed: scores are O(+-12), fp32 exp is exact enough and
// identical to softmax-with-max mathematically.
__global__ __launch_bounds__(256) void attn_kernel(
    const unsigned short* __restrict__ Qp, const unsigned short* __restrict__ Kp,
    const unsigned short* __restrict__ Vt, const int* __restrict__ mask,
    float* __restrict__ attn_out, unsigned short* __restrict__ ctx) {
  __shared__ unsigned short Ks[64][72];
  __shared__ unsigned short Vs[64][72];
  __shared__ unsigned short Ps[4][16][72];

  const int tid = threadIdx.x, lane = tid & 63, wid = tid >> 6;
  const int q0 = blockIdx.x * 64;
  const int bh = blockIdx.y;
  const int b = bh >> 4, h = bh & 15;

  const unsigned short* Qh = Qp + (size_t)b * LSEQ * DMOD + h * HDSZ;
  const unsigned short* Kh = Kp + (size_t)b * LSEQ * DMOD + h * HDSZ;
  const unsigned short* Vh = Vt + (size_t)b * DMOD * LSEQ + (size_t)h * HDSZ * LSEQ;
  const int* mb = mask + (size_t)b * LSEQ * LSEQ;
  float* ah = attn_out + (size_t)bh * LSEQ * LSEQ;

  const int wq0 = q0 + wid * 16;
  const int l15 = lane & 15, lg = lane >> 4;

  // Q as MFMA B-operand: lane holds Q[wq0+l15][ks*32 + lg*8 .. +7]
  short8 qf[2];
#pragma unroll
  for (int ks = 0; ks < 2; ks++)
    qf[ks] = *(const short8*)(Qh + (size_t)(wq0 + l15) * DMOD + ks * 32 + lg * 8);

  const int sr = tid >> 2, sc = (tid & 3) * 16;
  const int qrow = wq0 + l15;
  const float* mrow_f = nullptr;  // (unused; mask read as int4 below)
  (void)mrow_f;

  // ---------- sweep 1: denominators ----------
  float den = 0.f;
  short8 ka[2];
  {
    const unsigned short* s = Kh + (size_t)sr * DMOD + sc;
    ka[0] = *(const short8*)(s);
    ka[1] = *(const short8*)(s + 8);
  }
  for (int kt = 0; kt < LSEQ / 64; ++kt) {
    const int k0 = kt * 64;
    __syncthreads();
    *(short8*)&Ks[sr][sc] = ka[0];
    *(short8*)&Ks[sr][sc + 8] = ka[1];
    __syncthreads();
    if (kt + 1 < LSEQ / 64) {
      const unsigned short* s = Kh + (size_t)(k0 + 64 + sr) * DMOD + sc;
      ka[0] = *(const short8*)(s);
      ka[1] = *(const short8*)(s + 8);
    }
    short8 kf[4][2];
#pragma unroll
    for (int fn = 0; fn < 4; fn++)
#pragma unroll
      for (int ks = 0; ks < 2; ks++)
        kf[fn][ks] = *(const short8*)&Ks[fn * 16 + l15][ks * 32 + lg * 8];
#pragma unroll
    for (int fn = 0; fn < 4; fn++) {
      f32x4 s = (f32x4){0.f, 0.f, 0.f, 0.f};
      s = MFMA16(kf[fn][0], qf[0], s);
      s = MFMA16(kf[fn][1], qf[1], s);
      const int kcol = k0 + fn * 16 + lg * 4;
      i32x4 m4 = *(const i32x4*)(mb + (size_t)qrow * LSEQ + kcol);
      den += (m4[0] != 0) ? __expf(s[0]) : 0.f;
      den += (m4[1] != 0) ? __expf(s[1]) : 0.f;
      den += (m4[2] != 0) ? __expf(s[2]) : 0.f;
      den += (m4[3] != 0) ? __expf(s[3]) : 0.f;
    }
  }
  den += __shfl_xor(den, 16);
  den += __shfl_xor(den, 32);
  const float inv = 1.0f / den;

  // ---------- sweep 2: attn write + PV ----------
  f32x4 oacc[4];
#pragma unroll
  for (int fd = 0; fd < 4; fd++) oacc[fd] = (f32x4){0.f, 0.f, 0.f, 0.f};

  short8 va[2];
  {
    const unsigned short* s = Kh + (size_t)sr * DMOD + sc;
    ka[0] = *(const short8*)(s);
    ka[1] = *(const short8*)(s + 8);
    const unsigned short* sv = Vh + (size_t)sr * LSEQ + sc;
    va[0] = *(const short8*)(sv);
    va[1] = *(const short8*)(sv + 8);
  }
  for (int kt = 0; kt < LSEQ / 64; ++kt) {
    const int k0 = kt * 64;
    __syncthreads();
    *(short8*)&Ks[sr][sc] = ka[0];
    *(short8*)&Ks[sr][sc + 8] = ka[1];
    *(short8*)&Vs[sr][sc] = va[0];
    *(short8*)&Vs[sr][sc + 8] = va[1];
    __syncthreads();
    if (kt + 1 < LSEQ / 64) {
      const unsigned short* s = Kh + (size_t)(k0 + 64 + sr) * DMOD + sc;
      ka[0] = *(const short8*)(s);
      ka[1] = *(const short8*)(s + 8);
      const unsigned short* sv = Vh + (size_t)sr * LSEQ + k0 + 64 + sc;
      va[0] = *(const short8*)(sv);
      va[1] = *(const short8*)(sv + 8);
    }
    short8 kf[4][2];
#pragma unroll
    for (int fn = 0; fn < 4; fn++)
#pragma unroll
      for (int ks = 0; ks < 2; ks++)
        kf[fn][ks] = *(const short8*)&Ks[fn * 16 + l15][ks * 32 + lg * 8];
#pragma unroll
    for (int fn = 0; fn < 4; fn++) {
      f32x4 s = (f32x4){0.f, 0.f, 0.f, 0.f};
      s = MFMA16(kf[fn][0], qf[0], s);
      s = MFMA16(kf[fn][1], qf[1], s);
      const int kcol = k0 + fn * 16 + lg * 4;
      i32x4 m4 = *(const i32x4*)(mb + (size_t)qrow * LSEQ + kcol);
      f32x4 a;
      a[0] = (m4[0] != 0) ? __expf(s[0]) * inv : 0.f;
      a[1] = (m4[1] != 0) ? __expf(s[1]) * inv : 0.f;
      a[2] = (m4[2] != 0) ? __expf(s[2]) * inv : 0.f;
      a[3] = (m4[3] != 0) ? __expf(s[3]) * inv : 0.f;
      *(f32x4*)(ah + (size_t)qrow * LSEQ + kcol) = a;
      u16x4 pk;
      pk[0] = f2bf(a[0]); pk[1] = f2bf(a[1]); pk[2] = f2bf(a[2]); pk[3] = f2bf(a[3]);
      *(u16x4*)&Ps[wid][l15][fn * 16 + lg * 4] = pk;
    }
    // PV: A = Ps rows (wave-private LDS), B = Vs (d-major)
    short8 pa[2];
#pragma unroll
    for (int ks = 0; ks < 2; ks++)
      pa[ks] = *(const short8*)&Ps[wid][l15][ks * 32 + lg * 8];
#pragma unroll
    for (int fd = 0; fd < 4; fd++) {
#pragma unroll
      for (int ks = 0; ks < 2; ks++) {
        short8 vf = *(const short8*)&Vs[fd * 16 + l15][ks * 32 + lg * 8];
        oacc[fd] = MFMA16(pa[ks], vf, oacc[fd]);
      }
    }
  }

  unsigned short* ch = ctx + (size_t)b * LSEQ * DMOD + h * HDSZ;
#pragma unroll
  for (int fd = 0; fd < 4; fd++)
#pragma unroll
    for (int r = 0; r < 4; r++) {
      const int qr = wq0 + lg * 4 + r;
      ch[(size_t)qr * DMOD + fd * 16 + l15] = f2bf(oacc[fd][r]);
    }
}

// ---------------- launcher ----------------
extern "C" void kernel_launch(void* const* d_in, const int* in_sizes, int n_in,
                              void* d_out, int out_size, void* d_ws, size_t ws_size,
                              hipStream_t stream) {
  const float* q = (const float*)d_in[0];
  const float* k = (const float*)d_in[1];
  const float* v = (const float*)d_in[2];
  const int* mask = (const int*)d_in[3];
  const float* Wq = (const float*)d_in[4];
  const float* bq = (const float*)d_in[5];
  const float* Wk = (const float*)d_in[6];
  const float* bk = (const float*)d_in[7];
  const float* Wv = (const float*)d_in[8];
  const float* bv = (const float*)d_in[9];
  const float* Wo = (const float*)d_in[10];
  const float* bo = (const float*)d_in[11];

  float* out = (float*)d_out;
  float* attn = out + (size_t)BSZ * LSEQ * DMOD;

  const size_t NQKV = (size_t)BSZ * LSEQ * DMOD;
  const size_t NW = (size_t)DMOD * DMOD;

  // dead-before-attention scratch lives inside the attn output region
  unsigned short* qb = (unsigned short*)attn;
  unsigned short* kb = qb + NQKV;
  unsigned short* vb = kb + NQKV;
  unsigned short* Wqb = vb + NQKV;
  unsigned short* Wkb = Wqb + NW;
  unsigned short* Wvb = Wkb + NW;
  unsigned short* Vp = Wvb + NW;

  // survives attention -> d_ws
  unsigned short* Qp = (unsigned short*)d_ws;
  unsigned short* Kp = Qp + NQKV;
  unsigned short* Vt = Kp + NQKV;
  unsigned short* ctx = Vt + NQKV;
  unsigned short* Wob = ctx + NQKV;

  cvt_bf16<<<dim3(NQKV / 4 / 256), 256, 0, stream>>>(q, qb, (int)NQKV);
  cvt_bf16<<<dim3(NQKV / 4 / 256), 256, 0, stream>>>(k, kb, (int)NQKV);
  cvt_bf16<<<dim3(NQKV / 4 / 256), 256, 0, stream>>>(v, vb, (int)NQKV);
  cvt_bf16<<<dim3(NW / 4 / 256), 256, 0, stream>>>(Wq, Wqb, (int)NW);
  cvt_bf16<<<dim3(NW / 4 / 256), 256, 0, stream>>>(Wk, Wkb, (int)NW);
  cvt_bf16<<<dim3(NW / 4 / 256), 256, 0, stream>>>(Wv, Wvb, (int)NW);
  cvt_bf16<<<dim3(NW / 4 / 256), 256, 0, stream>>>(Wo, Wob, (int)NW);

  gemm_bt<0><<<dim3(32, 8, 3), 256, 0, stream>>>(
      qb, kb, vb, Wqb, Wkb, Wvb, bq, bk, bv, (void*)Qp, (void*)Kp, (void*)Vp,
      0.125f, 1.0f, 1.0f, BSZ * LSEQ, DMOD, DMOD);

  transpose_v<<<dim3(LSEQ / 64, DMOD / 64, BSZ), 256, 0, stream>>>(Vp, Vt);

  attn_kernel<<<dim3(LSEQ / 64, BSZ * NH), 256, 0, stream>>>(Qp, Kp, Vt, mask, attn, ctx);

  gemm_bt<1><<<dim3(32, 8, 1), 256, 0, stream>>>(
      ctx, ctx, ctx, Wob, Wob, Wob, bo, bo, bo, (void*)out, (void*)out, (void*)out,
      1.0f, 1.0f, 1.0f, BSZ * LSEQ, DMOD, DMOD);
}

// Round 3
// 364.619 us; speedup vs baseline: 1.6664x; 1.1240x over previous
//
#include <hip/hip_runtime.h>
#include <stdint.h>

#define BSZ 2
#define LSEQ 2048
#define DMOD 1024
#define NH 16
#define HDSZ 64

typedef __attribute__((ext_vector_type(8))) short short8;
typedef __attribute__((ext_vector_type(4))) float f32x4;
typedef __attribute__((ext_vector_type(4))) unsigned short u16x4;
typedef __attribute__((ext_vector_type(4))) int i32x4;

#define MFMA16(a, b, c) __builtin_amdgcn_mfma_f32_16x16x32_bf16((a), (b), (c), 0, 0, 0)

__device__ __forceinline__ unsigned short f2bf(float f) {
  union { float f; unsigned u; } x; x.f = f;
  unsigned u = x.u + 0x7fffu + ((x.u >> 16) & 1u);
  return (unsigned short)(u >> 16);
}

// ---------------- fp32 -> bf16 conversion ----------------
__global__ __launch_bounds__(256) void cvt_bf16(const float* __restrict__ in,
                                                unsigned short* __restrict__ out, int n) {
  int i = (blockIdx.x * 256 + threadIdx.x) * 4;
  if (i >= n) return;
  f32x4 v = *(const f32x4*)(in + i);
  u16x4 o;
  o[0] = f2bf(v[0]); o[1] = f2bf(v[1]); o[2] = f2bf(v[2]); o[3] = f2bf(v[3]);
  *(u16x4*)(out + i) = o;
}

// ---------------- GEMM: C = A * W^T + bias (A: MxK, W: NxK, bf16, fp32 acc) --------
template <int OUTF32>
__global__ __launch_bounds__(256) void gemm_bt(
    const unsigned short* __restrict__ A0, const unsigned short* __restrict__ A1,
    const unsigned short* __restrict__ A2,
    const unsigned short* __restrict__ W0, const unsigned short* __restrict__ W1,
    const unsigned short* __restrict__ W2,
    const float* __restrict__ b0, const float* __restrict__ b1, const float* __restrict__ b2,
    void* __restrict__ C0, void* __restrict__ C1, void* __restrict__ C2,
    float s0, float s1, float s2, int M, int N, int K) {
  const int z = blockIdx.z;
  const unsigned short* A = (z == 0) ? A0 : ((z == 1) ? A1 : A2);
  const unsigned short* W = (z == 0) ? W0 : ((z == 1) ? W1 : W2);
  const float* bias = (z == 0) ? b0 : ((z == 1) ? b1 : b2);
  void* Cout = (z == 0) ? C0 : ((z == 1) ? C1 : C2);
  const float scale = (z == 0) ? s0 : ((z == 1) ? s1 : s2);

  __shared__ unsigned short As[128 * 40];
  __shared__ unsigned short Bs[128 * 40];

  const int tid = threadIdx.x;
  const int lane = tid & 63;
  const int wid = tid >> 6;
  const int bm = blockIdx.x, bn = blockIdx.y;
  const int wm = (wid >> 1) * 64, wn = (wid & 1) * 64;

  f32x4 acc[4][4];
#pragma unroll
  for (int i = 0; i < 4; i++)
#pragma unroll
    for (int j = 0; j < 4; j++) acc[i][j] = (f32x4){0.f, 0.f, 0.f, 0.f};

  const int r0 = tid >> 2;
  const int c0 = (tid & 3) * 8;
  const unsigned short* Ag = A + (size_t)(bm * 128 + r0) * K + c0;
  const unsigned short* Bg = W + (size_t)(bn * 128 + r0) * K + c0;

  short8 va[2], vb[2];
#pragma unroll
  for (int j = 0; j < 2; j++) {
    va[j] = *(const short8*)(Ag + (size_t)(j * 64) * K);
    vb[j] = *(const short8*)(Bg + (size_t)(j * 64) * K);
  }

  for (int k0 = 0; k0 < K; k0 += 32) {
#pragma unroll
    for (int j = 0; j < 2; j++) {
      *(short8*)&As[(j * 64 + r0) * 40 + c0] = va[j];
      *(short8*)&Bs[(j * 64 + r0) * 40 + c0] = vb[j];
    }
    __syncthreads();
    if (k0 + 32 < K) {
#pragma unroll
      for (int j = 0; j < 2; j++) {
        va[j] = *(const short8*)(Ag + (size_t)(j * 64) * K + k0 + 32);
        vb[j] = *(const short8*)(Bg + (size_t)(j * 64) * K + k0 + 32);
      }
    }
    short8 af[4], bf[4];
#pragma unroll
    for (int i = 0; i < 4; i++)
      af[i] = *(const short8*)&As[(wm + i * 16 + (lane & 15)) * 40 + (lane >> 4) * 8];
#pragma unroll
    for (int i = 0; i < 4; i++)
      bf[i] = *(const short8*)&Bs[(wn + i * 16 + (lane & 15)) * 40 + (lane >> 4) * 8];
#pragma unroll
    for (int i = 0; i < 4; i++)
#pragma unroll
      for (int j = 0; j < 4; j++) acc[i][j] = MFMA16(af[i], bf[j], acc[i][j]);
    __syncthreads();
  }

  const int crow = bm * 128 + wm + (lane >> 4) * 4;
#pragma unroll
  for (int j = 0; j < 4; j++) {
    const int col = bn * 128 + wn + j * 16 + (lane & 15);
    const float bv = bias[col];
#pragma unroll
    for (int i = 0; i < 4; i++) {
#pragma unroll
      for (int r = 0; r < 4; r++) {
        float vvv = (acc[i][j][r] + bv) * scale;
        const size_t off = (size_t)(crow + i * 16 + r) * N + col;
        if (OUTF32)
          ((float*)Cout)[off] = vvv;
        else
          ((unsigned short*)Cout)[off] = f2bf(vvv);
      }
    }
  }
}

// ---------------- V transpose: (B,L,D) bf16 -> (B,D,L) bf16 ----------------
__global__ __launch_bounds__(256) void transpose_v(const unsigned short* __restrict__ Vp,
                                                   unsigned short* __restrict__ Vt) {
  __shared__ unsigned short T[64][72];
  const int tid = threadIdx.x;
  const int l0 = blockIdx.x * 64;
  const int d0 = blockIdx.y * 64;
  const int b = blockIdx.z;
  const int r = tid >> 2, c = (tid & 3) * 16;
  const unsigned short* src =
      Vp + (size_t)b * LSEQ * DMOD + (size_t)(l0 + r) * DMOD + d0 + c;
  *(short8*)&T[r][c] = *(const short8*)(src);
  *(short8*)&T[r][c + 8] = *(const short8*)(src + 8);
  __syncthreads();
  unsigned short tmp[16];
#pragma unroll
  for (int x = 0; x < 16; x++) tmp[x] = T[c + x][r];
  unsigned short* dst = Vt + (size_t)b * DMOD * LSEQ + (size_t)(d0 + r) * LSEQ + l0 + c;
  *(short8*)(dst) = *(short8*)&tmp[0];
  *(short8*)(dst + 8) = *(short8*)&tmp[8];
}

// ---------------- fused attention (v3: 2x2 q-split x k-split waves) ----------------
// grid: (L/128, B*H), 256 threads. Block owns 128 q-rows, stages 128 k-rows.
// Wave (qw = wid>>1, kw = wid&1): 64 q-rows x its own 64 k-half.
// kf LDS reads amortized over fq=4 q-fragments -> 24 b128 reads per 64 MFMA
// (3x less LDS/FLOP than v2). P per-wave in LDS; k-split O partials reduced
// once at the end. No max-subtraction needed (scores O(+-12), fp32-exact).
__global__ __launch_bounds__(256) void attn_kernel(
    const unsigned short* __restrict__ Qp, const unsigned short* __restrict__ Kp,
    const unsigned short* __restrict__ Vt, const int* __restrict__ mask,
    float* __restrict__ attn_out, unsigned short* __restrict__ ctx) {
  __shared__ unsigned short Ks[128][72];   // k-rows x d    (18.4 KB)
  __shared__ unsigned short Vs[64][136];   // d x k         (17.4 KB)
  __shared__ unsigned short Ps[4][64][72]; // per-wave q x k (36.9 KB)
  __shared__ float denbuf[2][128];

  const int tid = threadIdx.x, lane = tid & 63, wid = tid >> 6;
  const int kw = wid & 1, qw = wid >> 1;
  const int l15 = lane & 15, lg = lane >> 4;
  const int q0 = blockIdx.x * 128;
  const int bh = blockIdx.y;
  const int b = bh >> 4, h = bh & 15;

  const unsigned short* Qh = Qp + (size_t)b * LSEQ * DMOD + h * HDSZ;
  const unsigned short* Kh = Kp + (size_t)b * LSEQ * DMOD + h * HDSZ;
  const unsigned short* Vh = Vt + (size_t)b * DMOD * LSEQ + (size_t)h * HDSZ * LSEQ;
  const int* mb = mask + (size_t)b * LSEQ * LSEQ;
  float* ah = attn_out + (size_t)bh * LSEQ * LSEQ;

  const int wq0 = q0 + qw * 64;
  const int wk0 = kw * 64;

  // Q fragments (B-operand): lane holds Q[wq0+fq*16+l15][ks*32+lg*8 ..+7]
  short8 qf[4][2];
#pragma unroll
  for (int fq = 0; fq < 4; fq++)
#pragma unroll
    for (int ks = 0; ks < 2; ks++)
      qf[fq][ks] = *(const short8*)(Qh + (size_t)(wq0 + fq * 16 + l15) * DMOD +
                                    ks * 32 + lg * 8);

  // staging coordinates
  const int sr = tid >> 1, scc = (tid & 1) * 32;  // K: 128 rows x 64 d
  const int vr = tid >> 2, vc = (tid & 3) * 32;   // V: 64 d x 128 k

  // ---------------- sweep 1: denominators ----------------
  float den[4] = {0.f, 0.f, 0.f, 0.f};
  short8 ka[4];
#pragma unroll
  for (int j = 0; j < 4; j++)
    ka[j] = *(const short8*)(Kh + (size_t)sr * DMOD + scc + j * 8);

  for (int kt = 0; kt < LSEQ / 128; ++kt) {
    const int k0 = kt * 128;
    __syncthreads();
#pragma unroll
    for (int j = 0; j < 4; j++) *(short8*)&Ks[sr][scc + j * 8] = ka[j];
    __syncthreads();
    if (kt + 1 < LSEQ / 128) {
#pragma unroll
      for (int j = 0; j < 4; j++)
        ka[j] = *(const short8*)(Kh + (size_t)(k0 + 128 + sr) * DMOD + scc + j * 8);
    }
    short8 kf[4][2];
#pragma unroll
    for (int fn = 0; fn < 4; fn++)
#pragma unroll
      for (int ks = 0; ks < 2; ks++)
        kf[fn][ks] = *(const short8*)&Ks[wk0 + fn * 16 + l15][ks * 32 + lg * 8];
#pragma unroll
    for (int fq = 0; fq < 4; fq++) {
      const int qrow = wq0 + fq * 16 + l15;
      i32x4 m4[4];
#pragma unroll
      for (int fn = 0; fn < 4; fn++)
        m4[fn] = *(const i32x4*)(mb + (size_t)qrow * LSEQ + k0 + wk0 + fn * 16 + lg * 4);
#pragma unroll
      for (int fn = 0; fn < 4; fn++) {
        f32x4 s = (f32x4){0.f, 0.f, 0.f, 0.f};
        s = MFMA16(kf[fn][0], qf[fq][0], s);
        s = MFMA16(kf[fn][1], qf[fq][1], s);
        den[fq] += (m4[fn][0] != 0) ? __expf(s[0]) : 0.f;
        den[fq] += (m4[fn][1] != 0) ? __expf(s[1]) : 0.f;
        den[fq] += (m4[fn][2] != 0) ? __expf(s[2]) : 0.f;
        den[fq] += (m4[fn][3] != 0) ? __expf(s[3]) : 0.f;
      }
    }
  }
#pragma unroll
  for (int fq = 0; fq < 4; fq++) {
    den[fq] += __shfl_xor(den[fq], 16);
    den[fq] += __shfl_xor(den[fq], 32);
  }
  if (lg == 0) {
#pragma unroll
    for (int fq = 0; fq < 4; fq++) denbuf[kw][qw * 64 + fq * 16 + l15] = den[fq];
  }
  __syncthreads();
  float inv[4];
#pragma unroll
  for (int fq = 0; fq < 4; fq++) {
    const int ql = qw * 64 + fq * 16 + l15;
    inv[fq] = 1.0f / (denbuf[0][ql] + denbuf[1][ql]);
  }

  // ---------------- sweep 2: attn write + PV ----------------
  f32x4 oacc[4][4];
#pragma unroll
  for (int fq = 0; fq < 4; fq++)
#pragma unroll
    for (int fd = 0; fd < 4; fd++) oacc[fq][fd] = (f32x4){0.f, 0.f, 0.f, 0.f};

  short8 vva[4];
#pragma unroll
  for (int j = 0; j < 4; j++) {
    ka[j] = *(const short8*)(Kh + (size_t)sr * DMOD + scc + j * 8);
    vva[j] = *(const short8*)(Vh + (size_t)vr * LSEQ + vc + j * 8);
  }

  for (int kt = 0; kt < LSEQ / 128; ++kt) {
    const int k0 = kt * 128;
    __syncthreads();
#pragma unroll
    for (int j = 0; j < 4; j++) {
      *(short8*)&Ks[sr][scc + j * 8] = ka[j];
      *(short8*)&Vs[vr][vc + j * 8] = vva[j];
    }
    __syncthreads();
    if (kt + 1 < LSEQ / 128) {
#pragma unroll
      for (int j = 0; j < 4; j++) {
        ka[j] = *(const short8*)(Kh + (size_t)(k0 + 128 + sr) * DMOD + scc + j * 8);
        vva[j] = *(const short8*)(Vh + (size_t)vr * LSEQ + k0 + 128 + vc + j * 8);
      }
    }
    short8 kf[4][2];
#pragma unroll
    for (int fn = 0; fn < 4; fn++)
#pragma unroll
      for (int ks = 0; ks < 2; ks++)
        kf[fn][ks] = *(const short8*)&Ks[wk0 + fn * 16 + l15][ks * 32 + lg * 8];
#pragma unroll
    for (int fq = 0; fq < 4; fq++) {
      const int qrow = wq0 + fq * 16 + l15;
      i32x4 m4[4];
#pragma unroll
      for (int fn = 0; fn < 4; fn++)
        m4[fn] = *(const i32x4*)(mb + (size_t)qrow * LSEQ + k0 + wk0 + fn * 16 + lg * 4);
#pragma unroll
      for (int fn = 0; fn < 4; fn++) {
        f32x4 s = (f32x4){0.f, 0.f, 0.f, 0.f};
        s = MFMA16(kf[fn][0], qf[fq][0], s);
        s = MFMA16(kf[fn][1], qf[fq][1], s);
        f32x4 a;
        a[0] = (m4[fn][0] != 0) ? __expf(s[0]) * inv[fq] : 0.f;
        a[1] = (m4[fn][1] != 0) ? __expf(s[1]) * inv[fq] : 0.f;
        a[2] = (m4[fn][2] != 0) ? __expf(s[2]) * inv[fq] : 0.f;
        a[3] = (m4[fn][3] != 0) ? __expf(s[3]) * inv[fq] : 0.f;
        *(f32x4*)(ah + (size_t)qrow * LSEQ + k0 + wk0 + fn * 16 + lg * 4) = a;
        u16x4 pk;
        pk[0] = f2bf(a[0]); pk[1] = f2bf(a[1]); pk[2] = f2bf(a[2]); pk[3] = f2bf(a[3]);
        *(u16x4*)&Ps[wid][fq * 16 + l15][fn * 16 + lg * 4] = pk;
      }
    }
    // PV: A = P (q x k, wave-private), B = V (d x k)
    short8 pa2[4][2];
#pragma unroll
    for (int fq = 0; fq < 4; fq++)
#pragma unroll
      for (int ks = 0; ks < 2; ks++)
        pa2[fq][ks] = *(const short8*)&Ps[wid][fq * 16 + l15][ks * 32 + lg * 8];
#pragma unroll
    for (int fd = 0; fd < 4; fd++) {
      short8 vf0 = *(const short8*)&Vs[fd * 16 + l15][wk0 + lg * 8];
      short8 vf1 = *(const short8*)&Vs[fd * 16 + l15][wk0 + 32 + lg * 8];
#pragma unroll
      for (int fq = 0; fq < 4; fq++) {
        oacc[fq][fd] = MFMA16(pa2[fq][0], vf0, oacc[fq][fd]);
        oacc[fq][fd] = MFMA16(pa2[fq][1], vf1, oacc[fq][fd]);
      }
    }
  }

  // ---------------- k-split reduction + ctx store ----------------
  __syncthreads();  // Ps dead; reuse as fp32 reduction buffer (padded stride 65)
  float* red = (float*)&Ps[qw * 2][0][0];  // 18432 B region per pair >= 64*65*4
  if (kw == 1) {
#pragma unroll
    for (int fq = 0; fq < 4; fq++)
#pragma unroll
      for (int fd = 0; fd < 4; fd++)
#pragma unroll
        for (int r = 0; r < 4; r++)
          red[(fq * 16 + lg * 4 + r) * 65 + fd * 16 + l15] = oacc[fq][fd][r];
  }
  __syncthreads();
  if (kw == 0) {
    unsigned short* ch = ctx + (size_t)b * LSEQ * DMOD + h * HDSZ;
#pragma unroll
    for (int fq = 0; fq < 4; fq++)
#pragma unroll
      for (int fd = 0; fd < 4; fd++)
#pragma unroll
        for (int r = 0; r < 4; r++) {
          const int qr = wq0 + fq * 16 + lg * 4 + r;
          const float o = oacc[fq][fd][r] + red[(fq * 16 + lg * 4 + r) * 65 + fd * 16 + l15];
          ch[(size_t)qr * DMOD + fd * 16 + l15] = f2bf(o);
        }
  }
}

// ---------------- launcher ----------------
extern "C" void kernel_launch(void* const* d_in, const int* in_sizes, int n_in,
                              void* d_out, int out_size, void* d_ws, size_t ws_size,
                              hipStream_t stream) {
  const float* q = (const float*)d_in[0];
  const float* k = (const float*)d_in[1];
  const float* v = (const float*)d_in[2];
  const int* mask = (const int*)d_in[3];
  const float* Wq = (const float*)d_in[4];
  const float* bq = (const float*)d_in[5];
  const float* Wk = (const float*)d_in[6];
  const float* bk = (const float*)d_in[7];
  const float* Wv = (const float*)d_in[8];
  const float* bv = (const float*)d_in[9];
  const float* Wo = (const float*)d_in[10];
  const float* bo = (const float*)d_in[11];

  float* out = (float*)d_out;
  float* attn = out + (size_t)BSZ * LSEQ * DMOD;

  const size_t NQKV = (size_t)BSZ * LSEQ * DMOD;
  const size_t NW = (size_t)DMOD * DMOD;

  // dead-before-attention scratch lives inside the attn output region
  unsigned short* qb = (unsigned short*)attn;
  unsigned short* kb = qb + NQKV;
  unsigned short* vb = kb + NQKV;
  unsigned short* Wqb = vb + NQKV;
  unsigned short* Wkb = Wqb + NW;
  unsigned short* Wvb = Wkb + NW;
  unsigned short* Vp = Wvb + NW;

  // survives attention -> d_ws
  unsigned short* Qp = (unsigned short*)d_ws;
  unsigned short* Kp = Qp + NQKV;
  unsigned short* Vt = Kp + NQKV;
  unsigned short* ctx = Vt + NQKV;
  unsigned short* Wob = ctx + NQKV;

  cvt_bf16<<<dim3(NQKV / 4 / 256), 256, 0, stream>>>(q, qb, (int)NQKV);
  cvt_bf16<<<dim3(NQKV / 4 / 256), 256, 0, stream>>>(k, kb, (int)NQKV);
  cvt_bf16<<<dim3(NQKV / 4 / 256), 256, 0, stream>>>(v, vb, (int)NQKV);
  cvt_bf16<<<dim3(NW / 4 / 256), 256, 0, stream>>>(Wq, Wqb, (int)NW);
  cvt_bf16<<<dim3(NW / 4 / 256), 256, 0, stream>>>(Wk, Wkb, (int)NW);
  cvt_bf16<<<dim3(NW / 4 / 256), 256, 0, stream>>>(Wv, Wvb, (int)NW);
  cvt_bf16<<<dim3(NW / 4 / 256), 256, 0, stream>>>(Wo, Wob, (int)NW);

  gemm_bt<0><<<dim3(32, 8, 3), 256, 0, stream>>>(
      qb, kb, vb, Wqb, Wkb, Wvb, bq, bk, bv, (void*)Qp, (void*)Kp, (void*)Vp,
      0.125f, 1.0f, 1.0f, BSZ * LSEQ, DMOD, DMOD);

  transpose_v<<<dim3(LSEQ / 64, DMOD / 64, BSZ), 256, 0, stream>>>(Vp, Vt);

  attn_kernel<<<dim3(LSEQ / 128, BSZ * NH), 256, 0, stream>>>(Qp, Kp, Vt, mask, attn, ctx);

  gemm_bt<1><<<dim3(32, 8, 1), 256, 0, stream>>>(
      ctx, ctx, ctx, Wob, Wob, Wob, bo, bo, bo, (void*)out, (void*)out, (void*)out,
      1.0f, 1.0f, 1.0f, BSZ * LSEQ, DMOD, DMOD);
}